// Round 11
// baseline (87.992 us; speedup 1.0000x reference)
//
#include <hip/hip_runtime.h>

#define T_LEN 512

typedef float v2f __attribute__((ext_vector_type(2)));

// DPP self-permute: dst[lane] = src[perm(lane)]; old=0 + bound_ctrl=1 + full
// masks -> no tied copy, foldable into consumer (proven r8, absmax 0.0).
template <int CTRL>
__device__ __forceinline__ float dppf(float v) {
    return __int_as_float(__builtin_amdgcn_update_dpp(
        0, __float_as_int(v), CTRL, 0xF, 0xF, true));
}
#define DPP_X1   0xB1    // quad_perm [1,0,3,2] : lane^1 (exact, proven)
#define DPP_X2   0x4E    // quad_perm [2,3,0,1] : lane^2 (exact, proven)
#define DPP_X8   0x128   // row_ror:8          : lane^8 (exact, proven)
#define DPP_X3   0x1B    // quad_perm [3,2,1,0] : lane^3 (exact, documented)
#define DPP_HM   0x141   // row_half_mirror    : lane^7 (exact, documented)

// lane^4 = (lane^7)^3 : two chained exact DPPs.
__device__ __forceinline__ float dpp_x4(float v) { return dppf<DPP_X3>(dppf<DPP_HM>(v)); }

// Direction-proof ^16 pair-sum: permlane16_swap exchanges odd/even 16-lane rows
// between its two operands; with both inputs = v the RESULT PAIR at lane l is
// {v(l), v(l^16)} in some order -> sum is v(l)+v(l^16) under any convention.
// r9's inline-asm version FAILED: "+v"(t0),"+v"(t1) with t0==t1==v let the
// allocator coalesce both operands into ONE register (self-swap -> s=2*hn).
// The builtin returns two distinct SSA results (uint32x2 ext-vector; index
// with [0]/[1], NOT .x/.y — r10 compile fix) -> distinct registers, correct.
#if __has_builtin(__builtin_amdgcn_permlane16_swap)
__device__ __forceinline__ float swap16_sum(float v) {
    const unsigned i = __float_as_uint(v);
    const auto r = __builtin_amdgcn_permlane16_swap(i, i, false, false);
    return __uint_as_float(r[0]) + __uint_as_float(r[1]);
}
#else
// fallback: proven ds_swizzle XOR-16 (r7/r8, absmax 0.0)
__device__ __forceinline__ float swap16_sum(float v) {
    return v + __uint_as_float(__builtin_amdgcn_ds_swizzle(__float_as_uint(v), 0x401F));
}
#endif

// One wave = 2 batch elements (sub = lane bit 5), unit h = lane&31.
// Register-resident recurrence (r7-verified algebra, absmax 0.0):
//   y(l) = xp + sum_r Q_r(l^r), r in {0,1,2,3,8,9,10,11}
//   Q_r  = (w0-w2)*hn + (w1-w3)*b1 + w2*s + w3*s4
// where b1 = hn(l^4) [2 exact DPPs], s = hn(l)+hn(l^16) [permlane16 sum-trick],
// s4 = s(l^4) [2 DPPs]; wm = W_hh[h^r][h^m], m={0,4,16,20}, folded at load
// (algebraically exact: (w0-w2)*hn + w2*(hn+h16) = w0*hn + w2*h16).
// Gather is ALL-VALU: no DS op on the recurrence chain at all.
// Q packed in pairs -> 16 v_pk_fma_f32. 3-level DPP-fused combine tree.
__global__ void __launch_bounds__(256) __attribute__((amdgpu_waves_per_eu(2, 2)))
rnn_fused(
    const float* __restrict__ x,
    const float* __restrict__ W_ih,
    const float* __restrict__ W_hh,
    const float* __restrict__ b_ih,
    const float* __restrict__ b_hh,
    const float* __restrict__ fc_w,
    const float* __restrict__ fc_b,
    float* __restrict__ out)
{
    __shared__ __align__(16) float xbuf[4][2][34];  // x chunk broadcast (off critical path)

    const int tid  = threadIdx.x;
    const int wv   = tid >> 6;
    const int lane = tid & 63;
    const int sub  = lane >> 5;      // batch within wave
    const int h    = lane & 31;      // hidden unit owned by this lane
    const int b    = (blockIdx.x << 3) + (wv << 1) + sub;

    // wpk[k][m-slot] = {f(2k), f(2k+1)} over ri pairs; r = (ri&3)|((ri&4)<<1).
    // slot0 = w0-w2 (pairs hn), slot1 = w1-w3 (b1), slot2 = w2 (s), slot3 = w3 (s4).
    v2f wpk[4][4];
#pragma unroll
    for (int k = 0; k < 4; ++k) {
#pragma unroll
        for (int e = 0; e < 2; ++e) {
            const int ri = 2 * k + e;
            const int r  = (ri & 3) | ((ri & 4) << 1);
            const float* row = W_hh + (h ^ r) * 32;
            const float w0 = row[h];
            const float w1 = row[h ^ 4];
            const float w2 = row[h ^ 16];
            const float w3 = row[h ^ 20];
            wpk[k][0][e] = w0 - w2;
            wpk[k][1][e] = w1 - w3;
            wpk[k][2][e] = w2;
            wpk[k][3][e] = w3;
        }
    }

    const float wih  = W_ih[h];
    const float bias = b_ih[h] + b_hh[h];
    const float* xrow = x + (size_t)b * T_LEN;

    float* xw = &xbuf[wv][sub][0];
    xw[h] = xrow[h];            // stage x chunk 0

    float hn = 0.0f;            // register-resident recurrence state
#pragma unroll 1
    for (int c = 0; c < T_LEN / 32; ++c) {
        // anti-AGPR insurance (emits nothing when weights stay in arch VGPRs)
        asm volatile("" : "+v"(wpk[0][0]), "+v"(wpk[0][1]), "+v"(wpk[0][2]), "+v"(wpk[0][3]),
                          "+v"(wpk[1][0]), "+v"(wpk[1][1]), "+v"(wpk[1][2]), "+v"(wpk[1][3]));
        asm volatile("" : "+v"(wpk[2][0]), "+v"(wpk[2][1]), "+v"(wpk[2][2]), "+v"(wpk[2][3]),
                          "+v"(wpk[3][0]), "+v"(wpk[3][1]), "+v"(wpk[3][2]), "+v"(wpk[3][3]));
        float xn = 0.0f;
        const bool more = (c < T_LEN / 32 - 1);
        if (more) xn = xrow[(c + 1) * 32 + h];       // prefetch next x chunk
#pragma unroll
        for (int tc = 0; tc < 32; ++tc) {
            const float xt = xw[tc];                 // per-sub uniform broadcast read
            const float xp = __builtin_fmaf(xt, wih, bias);

            // ---- all-VALU gather (chain ~25 cyc, zero DS) ----
            const float b1 = dpp_x4(hn);             // hn(l^4)
            const float s  = swap16_sum(hn);         // hn(l) + hn(l^16)
            const float s4 = dpp_x4(s);              // hn(l^4) + hn(l^20)

            const v2f B0 = {hn, hn};
            const v2f B1 = {b1, b1};
            const v2f B2 = {s,  s };
            const v2f B3 = {s4, s4};

            // ---- 4 packed Q pairs: 16 v_pk_fma_f32 ----
            v2f Qp[4];
#pragma unroll
            for (int k = 0; k < 4; ++k) {
                v2f q = wpk[k][0] * B0;
                q = __builtin_elementwise_fma(wpk[k][1], B1, q);
                q = __builtin_elementwise_fma(wpk[k][2], B2, q);
                q = __builtin_elementwise_fma(wpk[k][3], B3, q);
                Qp[k] = q;
            }

            // combine tree: y(l) = xp + sum_r Q_r(l^r)
            const float A0  = Qp[0].x + dppf<DPP_X1>(Qp[0].y);   // r=0,1
            const float A2  = Qp[1].x + dppf<DPP_X1>(Qp[1].y);   // r=2,3
            const float A8  = Qp[2].x + dppf<DPP_X1>(Qp[2].y);   // r=8,9
            const float A10 = Qp[3].x + dppf<DPP_X1>(Qp[3].y);   // r=10,11
            const float B_0 = A0 + dppf<DPP_X2>(A2);
            const float B_8 = A8 + dppf<DPP_X2>(A10);
            const float y   = (xp + B_0) + dppf<DPP_X8>(B_8);

            // tanh(y) = 1 - 2/(exp(2y)+1)
            const float e  = __builtin_amdgcn_exp2f(y * 2.8853900817779268f);
            const float rc = __builtin_amdgcn_rcpf(e + 1.0f);
            hn = __builtin_fmaf(-2.0f, rc, 1.0f);
        }
        if (more) xw[h] = xn;                        // install prefetched x chunk
    }

    // out[b] = sum_h h_T[h]*fc_w[h] + fc_b ; butterfly within each 32-lane half
    float v = hn * fc_w[h];
#pragma unroll
    for (int m = 16; m >= 1; m >>= 1) v += __shfl_xor(v, m, 64);
    if (h == 0) out[b] = v + fc_b[0];
}

extern "C" void kernel_launch(void* const* d_in, const int* in_sizes, int n_in,
                              void* d_out, int out_size, void* d_ws, size_t ws_size,
                              hipStream_t stream) {
    const float* x    = (const float*)d_in[0];
    const float* W_ih = (const float*)d_in[1];
    const float* W_hh = (const float*)d_in[2];
    const float* b_ih = (const float*)d_in[3];
    const float* b_hh = (const float*)d_in[4];
    const float* fc_w = (const float*)d_in[5];
    const float* fc_b = (const float*)d_in[6];
    float* out = (float*)d_out;

    const int B = out_size;            // 4096
    dim3 grid(B / 8), block(256);      // 8 batch elements per 256-thread block
    hipLaunchKernelGGL(rnn_fused, grid, block, 0, stream,
                       x, W_ih, W_hh, b_ih, b_hh, fc_w, fc_b, out);
}

// Round 12
// 85.956 us; speedup vs baseline: 1.0237x; 1.0237x over previous
//
#include <hip/hip_runtime.h>

#define T_LEN 512

typedef float v2f __attribute__((ext_vector_type(2)));
typedef float v4f __attribute__((ext_vector_type(4)));

// DPP self-permute: dst[lane] = src[perm(lane)]; old=0 + bound_ctrl=1 + full
// masks -> no tied copy, foldable into consumer (proven r8/r11, absmax 0.0).
template <int CTRL>
__device__ __forceinline__ float dppf(float v) {
    return __int_as_float(__builtin_amdgcn_update_dpp(
        0, __float_as_int(v), CTRL, 0xF, 0xF, true));
}
#define DPP_X1   0xB1    // quad_perm [1,0,3,2] : lane^1 (proven)
#define DPP_X2   0x4E    // quad_perm [2,3,0,1] : lane^2 (proven)
#define DPP_X8   0x128   // row_ror:8          : lane^8 (proven)
#define DPP_X3   0x1B    // quad_perm [3,2,1,0] : lane^3 (proven r11)
#define DPP_HM   0x141   // row_half_mirror    : lane^7 (proven r11)

// lane^4 = (lane^7)^3 : two chained exact DPPs (proven r11).
__device__ __forceinline__ float dpp_x4(float v) { return dppf<DPP_X3>(dppf<DPP_HM>(v)); }

// Direction-proof ^16 pair-sum (proven r11, absmax 0.0): builtin returns two
// distinct SSA results -> {v(l), v(l^16)} in some order; sum is convention-free.
#if __has_builtin(__builtin_amdgcn_permlane16_swap)
__device__ __forceinline__ float swap16_sum(float v) {
    const unsigned i = __float_as_uint(v);
    const auto r = __builtin_amdgcn_permlane16_swap(i, i, false, false);
    return __uint_as_float(r[0]) + __uint_as_float(r[1]);
}
#else
__device__ __forceinline__ float swap16_sum(float v) {
    return v + __uint_as_float(__builtin_amdgcn_ds_swizzle(__float_as_uint(v), 0x401F));
}
#endif

// One wave = 2 batch elements (sub = lane bit 5), unit h = lane&31.
// r11-verified recurrence math (absmax 0.0). NEW in r12: ZERO DS ops in the
// loop — x comes from global as one dwordx4 quad per 4 steps (uniform address
// within each 32-lane sub -> broadcast), ping-pong prefetched 2 quads (8 steps,
// ~700cyc of compute) ahead of use so VMEM latency never touches the chain.
// Rationale: r4/r8/r11 all pinned at ~400cyc/SIMD-step despite different
// chains/instr-counts; the invariant was the per-step ds_read broadcast of x.
__global__ void __launch_bounds__(256) __attribute__((amdgpu_waves_per_eu(2, 2)))
rnn_fused(
    const float* __restrict__ x,
    const float* __restrict__ W_ih,
    const float* __restrict__ W_hh,
    const float* __restrict__ b_ih,
    const float* __restrict__ b_hh,
    const float* __restrict__ fc_w,
    const float* __restrict__ fc_b,
    float* __restrict__ out)
{
    const int tid  = threadIdx.x;
    const int wv   = tid >> 6;
    const int lane = tid & 63;
    const int sub  = lane >> 5;      // batch within wave
    const int h    = lane & 31;      // hidden unit owned by this lane
    const int b    = (blockIdx.x << 3) + (wv << 1) + sub;

    // wpk[k][m-slot] = {f(2k), f(2k+1)} over ri pairs; r = (ri&3)|((ri&4)<<1).
    // slot0 = w0-w2 (pairs hn), slot1 = w1-w3 (b1), slot2 = w2 (s), slot3 = w3 (s4).
    v2f wpk[4][4];
#pragma unroll
    for (int k = 0; k < 4; ++k) {
#pragma unroll
        for (int e = 0; e < 2; ++e) {
            const int ri = 2 * k + e;
            const int r  = (ri & 3) | ((ri & 4) << 1);
            const float* row = W_hh + (h ^ r) * 32;
            const float w0 = row[h];
            const float w1 = row[h ^ 4];
            const float w2 = row[h ^ 16];
            const float w3 = row[h ^ 20];
            wpk[k][0][e] = w0 - w2;
            wpk[k][1][e] = w1 - w3;
            wpk[k][2][e] = w2;
            wpk[k][3][e] = w3;
        }
    }

    const float wih  = W_ih[h];
    const float bias = b_ih[h] + b_hh[h];
    const float* xrow = x + (size_t)b * T_LEN;

    float hn = 0.0f;            // register-resident recurrence state

    // One recurrence step (r11-verified, absmax 0.0)
    auto step = [&](float xt) __attribute__((always_inline)) {
        const float xp = __builtin_fmaf(xt, wih, bias);
        const float b1 = dpp_x4(hn);             // hn(l^4)
        const float s  = swap16_sum(hn);         // hn(l) + hn(l^16)
        const float s4 = dpp_x4(s);              // hn(l^4) + hn(l^20)
        const v2f B0 = {hn, hn};
        const v2f B1 = {b1, b1};
        const v2f B2 = {s,  s };
        const v2f B3 = {s4, s4};
        v2f Qp[4];
#pragma unroll
        for (int k = 0; k < 4; ++k) {
            v2f q = wpk[k][0] * B0;
            q = __builtin_elementwise_fma(wpk[k][1], B1, q);
            q = __builtin_elementwise_fma(wpk[k][2], B2, q);
            q = __builtin_elementwise_fma(wpk[k][3], B3, q);
            Qp[k] = q;
        }
        const float A0  = Qp[0].x + dppf<DPP_X1>(Qp[0].y);   // r=0,1
        const float A2  = Qp[1].x + dppf<DPP_X1>(Qp[1].y);   // r=2,3
        const float A8  = Qp[2].x + dppf<DPP_X1>(Qp[2].y);   // r=8,9
        const float A10 = Qp[3].x + dppf<DPP_X1>(Qp[3].y);   // r=10,11
        const float B_0 = A0 + dppf<DPP_X2>(A2);
        const float B_8 = A8 + dppf<DPP_X2>(A10);
        const float y   = (xp + B_0) + dppf<DPP_X8>(B_8);
        const float e   = __builtin_amdgcn_exp2f(y * 2.8853900817779268f);
        const float rc  = __builtin_amdgcn_rcpf(e + 1.0f);
        hn = __builtin_fmaf(-2.0f, rc, 1.0f);
    };

    // x quads: ping-pong, prefetch distance 2 quads (= 8 steps of compute)
    v4f xc = *(const v4f*)(xrow);        // quad 0
    v4f xd = *(const v4f*)(xrow + 4);    // quad 1

#pragma unroll 1
    for (int q = 0; q < T_LEN / 4; q += 2) {
        // anti-AGPR insurance (emits nothing when weights stay in arch VGPRs)
        asm volatile("" : "+v"(wpk[0][0]), "+v"(wpk[0][1]), "+v"(wpk[0][2]), "+v"(wpk[0][3]),
                          "+v"(wpk[1][0]), "+v"(wpk[1][1]), "+v"(wpk[1][2]), "+v"(wpk[1][3]));
        asm volatile("" : "+v"(wpk[2][0]), "+v"(wpk[2][1]), "+v"(wpk[2][2]), "+v"(wpk[2][3]),
                          "+v"(wpk[3][0]), "+v"(wpk[3][1]), "+v"(wpk[3][2]), "+v"(wpk[3][3]));
        // clamped prefetch indices (tail loads re-read a valid quad, unused)
        const int qa = (q + 2 < T_LEN / 4) ? (q + 2) : q;
        const int qb = (q + 3 < T_LEN / 4) ? (q + 3) : q;
        const v4f pa = *(const v4f*)(xrow + qa * 4);
        const v4f pb = *(const v4f*)(xrow + qb * 4);

        step(xc.x); step(xc.y); step(xc.z); step(xc.w);   // quad q
        step(xd.x); step(xd.y); step(xd.z); step(xd.w);   // quad q+1

        xc = pa; xd = pb;
    }

    // out[b] = sum_h h_T[h]*fc_w[h] + fc_b ; butterfly within each 32-lane half
    float v = hn * fc_w[h];
#pragma unroll
    for (int m = 16; m >= 1; m >>= 1) v += __shfl_xor(v, m, 64);
    if (h == 0) out[b] = v + fc_b[0];
}

extern "C" void kernel_launch(void* const* d_in, const int* in_sizes, int n_in,
                              void* d_out, int out_size, void* d_ws, size_t ws_size,
                              hipStream_t stream) {
    const float* x    = (const float*)d_in[0];
    const float* W_ih = (const float*)d_in[1];
    const float* W_hh = (const float*)d_in[2];
    const float* b_ih = (const float*)d_in[3];
    const float* b_hh = (const float*)d_in[4];
    const float* fc_w = (const float*)d_in[5];
    const float* fc_b = (const float*)d_in[6];
    float* out = (float*)d_out;

    const int B = out_size;            // 4096
    dim3 grid(B / 8), block(256);      // 8 batch elements per 256-thread block
    hipLaunchKernelGGL(rnn_fused, grid, block, 0, stream,
                       x, W_ih, W_hh, b_ih, b_hh, fc_w, fc_b, out);
}